// Round 12
// baseline (461.805 us; speedup 1.0000x reference)
//
#include <hip/hip_runtime.h>
#include <hip/hip_fp8.h>
#include <hip/hip_bf16.h>

#define NND 50000
#define NE  1600000
#define TT  8
#define NBS ((NND + 255) / 256)   // 196 blocks over nodes
#define NBT2 ((NND + 63) / 64)    // 782 64-node tiles

typedef __attribute__((ext_vector_type(2))) float f32x2;

// ---------------- fp8 / bf16 helpers ----------------

template <int I>
__device__ inline float fp8tof(unsigned int u) {
#if __has_builtin(__builtin_amdgcn_cvt_f32_fp8)
  return __builtin_amdgcn_cvt_f32_fp8(u, I);   // byte-select must be literal
#else
  __hip_fp8_e4m3 v; v.__x = (unsigned char)(u >> (I * 8)); return (float)v;
#endif
}

// packed: 2 fp8 -> 2 f32 in one instruction (word W: bytes 2W,2W+1 -> x,y)
template <bool W>
__device__ inline f32x2 cvtpk2(unsigned int u) {
#if __has_builtin(__builtin_amdgcn_cvt_pk_f32_fp8)
  return __builtin_amdgcn_cvt_pk_f32_fp8(u, W);
#else
  f32x2 r;
  r.x = fp8tof<W ? 2 : 0>(u);
  r.y = fp8tof<W ? 3 : 1>(u);
  return r;
#endif
}

__device__ inline unsigned int pk4_fp8(float a, float b, float c, float d) {
#if __has_builtin(__builtin_amdgcn_cvt_pk_fp8_f32)
  int v = 0;
  v = __builtin_amdgcn_cvt_pk_fp8_f32(a, b, v, false);  // bytes 0,1
  v = __builtin_amdgcn_cvt_pk_fp8_f32(c, d, v, true);   // bytes 2,3
  return (unsigned int)v;
#else
  __hip_fp8_e4m3 qa(a), qb(b), qc(c), qd(d);
  return (unsigned int)qa.__x | ((unsigned int)qb.__x << 8) |
         ((unsigned int)qc.__x << 16) | ((unsigned int)qd.__x << 24);
#endif
}

__device__ inline unsigned int pkbf(float a, float b) {
  __hip_bfloat16 ha = __float2bfloat16(a), hb = __float2bfloat16(b);
  unsigned short ua = *(unsigned short*)&ha, ub = *(unsigned short*)&hb;
  return (unsigned int)ua | ((unsigned int)ub << 16);
}
__device__ inline float bl(unsigned int w) { return __uint_as_float(w << 16); }
__device__ inline float bh(unsigned int w) { return __uint_as_float(w & 0xffff0000u); }

// ---------------- preprocessing ----------------

__global__ void k_init(int* __restrict__ deg, float* __restrict__ ppool) {
  int i = blockIdx.x * 256 + threadIdx.x;
  if (i < NND) deg[i] = 1;              // self-loop
  if (i < TT * 64) ppool[i] = 0.f;
}

// degree histogram; atomic old-value = unique slot rank (>=1; slot 0 = self-loop)
__global__ void k_deg(const int* __restrict__ ei, int* __restrict__ deg,
                      int* __restrict__ rank) {
  int e = blockIdx.x * 256 + threadIdx.x;
  if (e < NE) rank[e] = atomicAdd(&deg[ei[NE + e]], 1);
}

__global__ void k_dinv(const int* __restrict__ deg, float* __restrict__ dinv) {
  int n = blockIdx.x * 256 + threadIdx.x;
  if (n < NND) dinv[n] = rsqrtf((float)deg[n]);
}

__global__ void k_scan1(const int* __restrict__ deg, int* __restrict__ bsum) {
  __shared__ int sh[256];
  int n = blockIdx.x * 256 + threadIdx.x;
  sh[threadIdx.x] = (n < NND) ? deg[n] : 0;
  __syncthreads();
  for (int o = 128; o > 0; o >>= 1) {
    if (threadIdx.x < o) sh[threadIdx.x] += sh[threadIdx.x + o];
    __syncthreads();
  }
  if (threadIdx.x == 0) bsum[blockIdx.x] = sh[0];
}

__global__ void k_scan2(const int* __restrict__ bsum, int* __restrict__ boff) {
  __shared__ int sh[256];
  int tid = threadIdx.x;
  int v = (tid < NBS) ? bsum[tid] : 0;
  sh[tid] = v;
  __syncthreads();
  for (int o = 1; o < 256; o <<= 1) {
    int t = (tid >= o) ? sh[tid - o] : 0;
    __syncthreads();
    sh[tid] += t;
    __syncthreads();
  }
  boff[tid] = sh[tid] - v;  // exclusive
}

__global__ void k_scan3(const int* __restrict__ deg, const int* __restrict__ boff,
                        int* __restrict__ offs, int* __restrict__ csr) {
  __shared__ int sh[256];
  int tid = threadIdx.x;
  int n = blockIdx.x * 256 + tid;
  int v = (n < NND) ? deg[n] : 0;
  sh[tid] = v;
  __syncthreads();
  for (int o = 1; o < 256; o <<= 1) {
    int t2 = (tid >= o) ? sh[tid - o] : 0;
    __syncthreads();
    sh[tid] += t2;
    __syncthreads();
  }
  if (n < NND) {
    int x = boff[blockIdx.x] + sh[tid] - v;  // exclusive global offset
    offs[n] = x;
    csr[x] = n;   // slot 0 = self-loop
  }
}

// atomic-free scatter; 2 dst-range passes keep the csr write window L2-resident
__global__ void k_scatter(const int* __restrict__ ei, const int* __restrict__ offs,
                          const int* __restrict__ rank, int* __restrict__ csr,
                          int lo, int hi) {
  int e = blockIdx.x * 256 + threadIdx.x;
  if (e < NE) {
    int d = ei[NE + e];
    if (d >= lo && d < hi) csr[offs[d] + rank[e]] = ei[e];
  }
}

// x_seq [T][N][3] f32 -> xs2 [N][T] uint2 (4 bf16: x0,x1,x2,pad, pre-scaled by dinv)
__global__ void k_xsb(const float* __restrict__ x, const float* __restrict__ dinv,
                      uint2* __restrict__ xs2) {
  int g = blockIdx.x * 256 + threadIdx.x;
  if (g >= NND * TT) return;
  int n = g >> 3, t = g & 7;
  const float* xx = x + ((size_t)t * NND + n) * 3;
  float dn = dinv[n];
  xs2[(size_t)n * 8 + t] = make_uint2(pkbf(xx[0] * dn, xx[1] * dn),
                                      pkbf(xx[2] * dn, 0.f));
}

// ---------------- fused layer 1: aggregate + W1 + ReLU + fp8 pack ----------------

// thread (n, tp): tp = t-pair. uint4 gather = both timesteps per 16B load.
__global__ void k_yh1(const int* __restrict__ offs, const int* __restrict__ deg,
                      const int* __restrict__ csr, const uint4* __restrict__ xs4,
                      const float* __restrict__ dinv, const float* __restrict__ W1,
                      const float* __restrict__ b1, uint4* __restrict__ h1w) {
  int g = blockIdx.x * 256 + threadIdx.x;
  int n = g >> 2, tp = g & 3;
  if (n >= NND) return;
  int o0 = offs[n], d = deg[n];
  float a0 = 0.f, a1 = 0.f, a2 = 0.f;   // t = 2tp
  float c0 = 0.f, c1 = 0.f, c2 = 0.f;   // t = 2tp+1
  int i = 0;
  for (; i + 4 <= d; i += 4) {
    int s0 = csr[o0 + i], s1 = csr[o0 + i + 1];
    int s2 = csr[o0 + i + 2], s3 = csr[o0 + i + 3];
    uint4 u0 = xs4[(size_t)s0 * 4 + tp];
    uint4 u1 = xs4[(size_t)s1 * 4 + tp];
    uint4 u2 = xs4[(size_t)s2 * 4 + tp];
    uint4 u3 = xs4[(size_t)s3 * 4 + tp];
    a0 += bl(u0.x) + bl(u1.x) + bl(u2.x) + bl(u3.x);
    a1 += bh(u0.x) + bh(u1.x) + bh(u2.x) + bh(u3.x);
    a2 += bl(u0.y) + bl(u1.y) + bl(u2.y) + bl(u3.y);
    c0 += bl(u0.z) + bl(u1.z) + bl(u2.z) + bl(u3.z);
    c1 += bh(u0.z) + bh(u1.z) + bh(u2.z) + bh(u3.z);
    c2 += bl(u0.w) + bl(u1.w) + bl(u2.w) + bl(u3.w);
  }
  for (; i < d; ++i) {
    uint4 u = xs4[(size_t)csr[o0 + i] * 4 + tp];
    a0 += bl(u.x); a1 += bh(u.x); a2 += bl(u.y);
    c0 += bl(u.z); c1 += bh(u.z); c2 += bl(u.w);
  }
  float dn = dinv[n];
#pragma unroll
  for (int j = 0; j < 2; ++j) {
    float y0 = (j ? c0 : a0) * dn, y1 = (j ? c1 : a1) * dn, y2 = (j ? c2 : a2) * dn;
    size_t base = ((size_t)(2 * tp + j) * NND + n) * 4;
#pragma unroll
    for (int k = 0; k < 4; ++k) {
      float vv[16];
#pragma unroll
      for (int m = 0; m < 16; ++m) {
        int c = k * 16 + m;
        float hv = fmaf(y2, W1[128 + c], fmaf(y1, W1[64 + c], fmaf(y0, W1[c], b1[c])));
        vv[m] = fmaxf(hv, 0.f) * dn;
      }
      uint4 o;
      o.x = pk4_fp8(vv[0], vv[1], vv[2], vv[3]);
      o.y = pk4_fp8(vv[4], vv[5], vv[6], vv[7]);
      o.z = pk4_fp8(vv[8], vv[9], vv[10], vv[11]);
      o.w = pk4_fp8(vv[12], vv[13], vv[14], vv[15]);
      h1w[base + k] = o;
    }
  }
}

// ---------------- fused layer 2: gather + W2 GEMM + relu + pool ----------------

// packed converts + packed adds: 1 VALU instr/value
#define ACCPK(u) do { \
  acc2[0] += cvtpk2<false>((u).x); acc2[1] += cvtpk2<true>((u).x); \
  acc2[2] += cvtpk2<false>((u).y); acc2[3] += cvtpk2<true>((u).y); \
  acc2[4] += cvtpk2<false>((u).z); acc2[5] += cvtpk2<true>((u).z); \
  acc2[6] += cvtpk2<false>((u).w); acc2[7] += cvtpk2<true>((u).w); \
} while (0)

// XCD-pinned (t = blockIdx.x & 7): each timestep's 3.2MB h1 slice lives on one
// XCD's L2 (round-10: FETCH 266->50MB). THIS ROUND: As tile stored as bf16
// (uint = 2xbf16, row stride 34 uints = 8.7KB vs 17.4KB f32) -> block LDS
// 34.3->25.3KB -> 6 blocks/CU (24 waves, 75% cap) vs 4 (41% measured).
// Round-11 counters showed VALU 54% at occupancy 41% = dep-chain stalls with
// only ~3 waves/SIMD; more resident waves is the fix.
__launch_bounds__(256, 6)
__global__ void k_l2f(const int* __restrict__ offs, const int* __restrict__ deg,
                      const int* __restrict__ csr, const uint4* __restrict__ h1all,
                      const float* __restrict__ dinv, const float* __restrict__ W2,
                      const float* __restrict__ b2, float* __restrict__ ppool) {
  __shared__ unsigned int As2[64 * 34];  // 8.7 KB, bf16 pairs, stride 34 uints
  __shared__ float Ws[64 * 64];          // 16 KB, W2^T, chunk-swizzled
  __shared__ float pool[64];
  int tid = threadIdx.x;
  int t = blockIdx.x & 7;
  int rows0 = (blockIdx.x >> 3) * 64;
  const uint4* h1v = h1all + (size_t)t * NND * 4;
  if (tid < 64) pool[tid] = 0.f;
  // Ws[j][swz(k)] = W2[k][j]
  for (int i = 0; i < 16; ++i) {
    int idx = i * 256 + tid;
    int k = idx >> 6, j = idx & 63;
    Ws[j * 64 + (((k >> 2) ^ ((j >> 3) & 7)) << 2) + (k & 3)] = W2[idx];
  }

  // ---- phase 1: gather (node row = tid>>2, q = tid&3 -> k = q*16+m) ----
  int row = tid >> 2, q = tid & 3;
  int n = rows0 + row;
  f32x2 acc2[8];
#pragma unroll
  for (int m = 0; m < 8; ++m) acc2[m] = (f32x2)(0.f);
  if (n < NND) {
    int o0 = offs[n], d = deg[n];
    int i = 0;
    for (; i + 4 <= d; i += 4) {
      int s0 = csr[o0 + i], s1 = csr[o0 + i + 1];
      int s2 = csr[o0 + i + 2], s3 = csr[o0 + i + 3];
      uint4 u0 = h1v[(size_t)s0 * 4 + q];
      uint4 u1 = h1v[(size_t)s1 * 4 + q];
      uint4 u2 = h1v[(size_t)s2 * 4 + q];
      uint4 u3 = h1v[(size_t)s3 * 4 + q];
      ACCPK(u0); ACCPK(u1); ACCPK(u2); ACCPK(u3);
    }
    for (; i < d; ++i) {
      uint4 u = h1v[(size_t)csr[o0 + i] * 4 + q];
      ACCPK(u);
    }
  }
  float dn = (n < NND) ? dinv[n] : 0.f;
  // pack 16 f32 -> 8 uints (bf16 pairs), store as 4x uint2 (8B aligned: 136%8=0)
#pragma unroll
  for (int j = 0; j < 4; ++j) {
    uint2 s;
    s.x = pkbf(acc2[2 * j].x * dn, acc2[2 * j].y * dn);
    s.y = pkbf(acc2[2 * j + 1].x * dn, acc2[2 * j + 1].y * dn);
    *(uint2*)&As2[row * 34 + q * 8 + j * 2] = s;
  }
  __syncthreads();

  // ---- phase 2: As[64,64](bf16) @ W2 -> relu+bias -> pool ----
  int rowg = tid >> 3, colg = tid & 7;
  int r0 = rowg * 2, c0 = colg * 8;
  float gac[2][8];
  for (int a = 0; a < 2; ++a)
    for (int b = 0; b < 8; ++b) gac[a][b] = 0.f;
  for (int k4 = 0; k4 < 16; ++k4) {
    float4 w[8];
    for (int cc = 0; cc < 8; ++cc)
      w[cc] = *(const float4*)&Ws[(c0 + cc) * 64 + ((k4 ^ colg) << 2)];
    for (int rr = 0; rr < 2; ++rr) {
      int r = r0 + rr;
      uint2 ab = *(const uint2*)&As2[r * 34 + k4 * 2];
      float4 av = make_float4(bl(ab.x), bh(ab.x), bl(ab.y), bh(ab.y));
      for (int cc = 0; cc < 8; ++cc) {
        gac[rr][cc] += av.x * w[cc].x;
        gac[rr][cc] += av.y * w[cc].y;
        gac[rr][cc] += av.z * w[cc].z;
        gac[rr][cc] += av.w * w[cc].w;
      }
    }
  }

  float b2c[8];
  for (int cc = 0; cc < 8; ++cc) b2c[cc] = b2[c0 + cc];
  float csum[8];
  for (int cc = 0; cc < 8; ++cc) csum[cc] = 0.f;
  for (int rr = 0; rr < 2; ++rr) {
    if (rows0 + r0 + rr < NND) {
      for (int cc = 0; cc < 8; ++cc)
        csum[cc] += fmaxf(gac[rr][cc] + b2c[cc], 0.f);
    }
  }
  for (int cc = 0; cc < 8; ++cc) atomicAdd(&pool[c0 + cc], csum[cc]);
  __syncthreads();
  if (tid < 64) atomicAdd(&ppool[t * 64 + tid], pool[tid]);
}

// ---------------- GRU + fc ----------------

__global__ void k_twih(const float* __restrict__ w, float* __restrict__ wt) {
  int g = blockIdx.x * 256 + threadIdx.x;
  if (g < 384 * 64) { int r = g >> 6, k = g & 63; wt[k * 384 + r] = w[g]; }
}
__global__ void k_twhh(const float* __restrict__ w, float* __restrict__ wt) {
  int g = blockIdx.x * 256 + threadIdx.x;
  if (g < 384 * 128) { int r = g >> 7, k = g & 127; wt[k * 384 + r] = w[g]; }
}

__launch_bounds__(384, 2)
__global__ void k_gru(const float* __restrict__ ppool, const float* __restrict__ wihT,
                      const float* __restrict__ whhT, const float* __restrict__ b_ih,
                      const float* __restrict__ b_hh, const float* __restrict__ fc_w,
                      const float* __restrict__ fc_b, float* __restrict__ out) {
  __shared__ float x[64], h[128], gi_s[384], gh_s[384], red[128];
  int j = threadIdx.x;  // 0..383
  float wih[64];
#pragma unroll
  for (int k = 0; k < 64; ++k) wih[k] = wihT[k * 384 + j];
  float whh[128];
#pragma unroll
  for (int k = 0; k < 128; ++k) whh[k] = whhT[k * 384 + j];
  float bi = b_ih[j], bh2 = b_hh[j];
  if (j < 128) h[j] = 0.f;
  const float invn = 1.0f / (float)NND;
  for (int t = 0; t < TT; ++t) {
    if (j < 64) x[j] = ppool[t * 64 + j] * invn;
    __syncthreads();
    float gi = bi, gh = bh2;
#pragma unroll
    for (int k4 = 0; k4 < 16; ++k4) {
      float4 xv = *(const float4*)&x[k4 * 4];
      gi = fmaf(wih[k4 * 4 + 0], xv.x, gi);
      gi = fmaf(wih[k4 * 4 + 1], xv.y, gi);
      gi = fmaf(wih[k4 * 4 + 2], xv.z, gi);
      gi = fmaf(wih[k4 * 4 + 3], xv.w, gi);
    }
#pragma unroll
    for (int k4 = 0; k4 < 32; ++k4) {
      float4 hv = *(const float4*)&h[k4 * 4];
      gh = fmaf(whh[k4 * 4 + 0], hv.x, gh);
      gh = fmaf(whh[k4 * 4 + 1], hv.y, gh);
      gh = fmaf(whh[k4 * 4 + 2], hv.z, gh);
      gh = fmaf(whh[k4 * 4 + 3], hv.w, gh);
    }
    gi_s[j] = gi;
    gh_s[j] = gh;
    __syncthreads();
    if (j < 128) {
      float r = 1.f / (1.f + expf(-(gi_s[j] + gh_s[j])));
      float z = 1.f / (1.f + expf(-(gi_s[128 + j] + gh_s[128 + j])));
      float nn = tanhf(gi_s[256 + j] + r * gh_s[256 + j]);
      h[j] = (1.f - z) * nn + z * h[j];
    }
    __syncthreads();
  }
  if (j < 128) red[j] = h[j] * fc_w[j];
  __syncthreads();
  for (int o = 64; o > 0; o >>= 1) {
    if (j < o) red[j] += red[j + o];
    __syncthreads();
  }
  if (j == 0) out[0] = red[0] + fc_b[0];
}

// ---------------- launch ----------------

extern "C" void kernel_launch(void* const* d_in, const int* in_sizes, int n_in,
                              void* d_out, int out_size, void* d_ws, size_t ws_size,
                              hipStream_t stream) {
  const float* x_seq = (const float*)d_in[0];
  const int*   ei    = (const int*)d_in[1];
  const float* W1    = (const float*)d_in[2];
  const float* b1    = (const float*)d_in[3];
  const float* W2    = (const float*)d_in[4];
  const float* b2    = (const float*)d_in[5];
  const float* w_ih  = (const float*)d_in[6];
  const float* w_hh  = (const float*)d_in[7];
  const float* b_ih  = (const float*)d_in[8];
  const float* b_hh  = (const float*)d_in[9];
  const float* fc_w  = (const float*)d_in[10];
  const float* fc_b  = (const float*)d_in[11];
  float* out = (float*)d_out;

  char* p = (char*)d_ws;
  size_t off = 0;
  auto carve = [&](size_t bytes) -> char* {
    char* q = p + off;
    off += (bytes + 255) & ~(size_t)255;
    return q;
  };
  int*   deg    = (int*)carve((size_t)NND * 4);
  float* dinv   = (float*)carve((size_t)NND * 4);
  int*   offs   = (int*)carve((size_t)NND * 4);
  int*   bsum   = (int*)carve(256 * 4);
  int*   boff   = (int*)carve(256 * 4);
  int*   csr    = (int*)carve((size_t)(NE + NND) * 4);
  uint2* xs2    = (uint2*)carve((size_t)NND * 8 * 8);        // 3.2 MB
  float* ppool  = (float*)carve((size_t)TT * 64 * 4);
  float* wihT   = (float*)carve((size_t)384 * 64 * 4);
  float* whhT   = (float*)carve((size_t)384 * 128 * 4);
  char*  tail   = carve((size_t)TT * NND * 64);              // 25.6 MB: h1all
  uint4* h1all  = (uint4*)tail;
  int*   rank   = (int*)tail;   // alias: rank dead before h1all's first write

  k_init<<<NBS, 256, 0, stream>>>(deg, ppool);
  k_deg<<<(NE + 255) / 256, 256, 0, stream>>>(ei, deg, rank);
  k_dinv<<<NBS, 256, 0, stream>>>(deg, dinv);
  k_scan1<<<NBS, 256, 0, stream>>>(deg, bsum);
  k_scan2<<<1, 256, 0, stream>>>(bsum, boff);
  k_scan3<<<NBS, 256, 0, stream>>>(deg, boff, offs, csr);
  // 2 atomic-free dst-range passes (csr window ~3.3MB, L2-resident)
  for (int pp = 0; pp < 2; ++pp) {
    int lo = pp * (NND / 2), hi = (pp == 1) ? NND : (NND / 2);
    k_scatter<<<(NE + 255) / 256, 256, 0, stream>>>(ei, offs, rank, csr, lo, hi);
  }
  k_xsb<<<(NND * TT + 255) / 256, 256, 0, stream>>>(x_seq, dinv, xs2);
  k_twih<<<(384 * 64 + 255) / 256, 256, 0, stream>>>(w_ih, wihT);
  k_twhh<<<(384 * 128 + 255) / 256, 256, 0, stream>>>(w_hh, whhT);
  // fused layer-1, all t (rank dead from here; h1all reuses its space)
  k_yh1<<<(NND * 4 + 255) / 256, 256, 0, stream>>>(offs, deg, csr,
                                                   (const uint4*)xs2, dinv,
                                                   W1, b1, h1all);
  // fused layer-2 + pool, ALL t, XCD-pinned t-slices
  k_l2f<<<TT * NBT2, 256, 0, stream>>>(offs, deg, csr, h1all, dinv, W2, b2, ppool);

  k_gru<<<1, 384, 0, stream>>>(ppool, wihT, whhT, b_ih, b_hh, fc_w, fc_b, out);
}

// Round 13
// 392.212 us; speedup vs baseline: 1.1774x; 1.1774x over previous
//
#include <hip/hip_runtime.h>
#include <hip/hip_fp8.h>
#include <hip/hip_bf16.h>

#define NND 50000
#define NE  1600000
#define TT  8
#define NBS ((NND + 255) / 256)   // 196 blocks over nodes
#define NBT2 ((NND + 63) / 64)    // 782 64-node tiles

typedef __attribute__((ext_vector_type(2))) float f32x2;

// ---------------- fp8 / bf16 helpers ----------------

template <int I>
__device__ inline float fp8tof(unsigned int u) {
#if __has_builtin(__builtin_amdgcn_cvt_f32_fp8)
  return __builtin_amdgcn_cvt_f32_fp8(u, I);   // byte-select must be literal
#else
  __hip_fp8_e4m3 v; v.__x = (unsigned char)(u >> (I * 8)); return (float)v;
#endif
}

// packed: 2 fp8 -> 2 f32 in one instruction (word W: bytes 2W,2W+1 -> x,y)
template <bool W>
__device__ inline f32x2 cvtpk2(unsigned int u) {
#if __has_builtin(__builtin_amdgcn_cvt_pk_f32_fp8)
  return __builtin_amdgcn_cvt_pk_f32_fp8(u, W);
#else
  f32x2 r;
  r.x = fp8tof<W ? 2 : 0>(u);
  r.y = fp8tof<W ? 3 : 1>(u);
  return r;
#endif
}

__device__ inline unsigned int pk4_fp8(float a, float b, float c, float d) {
#if __has_builtin(__builtin_amdgcn_cvt_pk_fp8_f32)
  int v = 0;
  v = __builtin_amdgcn_cvt_pk_fp8_f32(a, b, v, false);  // bytes 0,1
  v = __builtin_amdgcn_cvt_pk_fp8_f32(c, d, v, true);   // bytes 2,3
  return (unsigned int)v;
#else
  __hip_fp8_e4m3 qa(a), qb(b), qc(c), qd(d);
  return (unsigned int)qa.__x | ((unsigned int)qb.__x << 8) |
         ((unsigned int)qc.__x << 16) | ((unsigned int)qd.__x << 24);
#endif
}

__device__ inline unsigned int pkbf(float a, float b) {
  __hip_bfloat16 ha = __float2bfloat16(a), hb = __float2bfloat16(b);
  unsigned short ua = *(unsigned short*)&ha, ub = *(unsigned short*)&hb;
  return (unsigned int)ua | ((unsigned int)ub << 16);
}
__device__ inline float bl(unsigned int w) { return __uint_as_float(w << 16); }
__device__ inline float bh(unsigned int w) { return __uint_as_float(w & 0xffff0000u); }

// ---------------- preprocessing ----------------

__global__ void k_init(int* __restrict__ deg, float* __restrict__ ppool) {
  int i = blockIdx.x * 256 + threadIdx.x;
  if (i < NND) deg[i] = 1;              // self-loop
  if (i < TT * 64) ppool[i] = 0.f;
}

// degree histogram; atomic old-value = unique slot rank (>=1; slot 0 = self-loop)
__global__ void k_deg(const int* __restrict__ ei, int* __restrict__ deg,
                      int* __restrict__ rank) {
  int e = blockIdx.x * 256 + threadIdx.x;
  if (e < NE) rank[e] = atomicAdd(&deg[ei[NE + e]], 1);
}

__global__ void k_dinv(const int* __restrict__ deg, float* __restrict__ dinv) {
  int n = blockIdx.x * 256 + threadIdx.x;
  if (n < NND) dinv[n] = rsqrtf((float)deg[n]);
}

__global__ void k_scan1(const int* __restrict__ deg, int* __restrict__ bsum) {
  __shared__ int sh[256];
  int n = blockIdx.x * 256 + threadIdx.x;
  sh[threadIdx.x] = (n < NND) ? deg[n] : 0;
  __syncthreads();
  for (int o = 128; o > 0; o >>= 1) {
    if (threadIdx.x < o) sh[threadIdx.x] += sh[threadIdx.x + o];
    __syncthreads();
  }
  if (threadIdx.x == 0) bsum[blockIdx.x] = sh[0];
}

__global__ void k_scan2(const int* __restrict__ bsum, int* __restrict__ boff) {
  __shared__ int sh[256];
  int tid = threadIdx.x;
  int v = (tid < NBS) ? bsum[tid] : 0;
  sh[tid] = v;
  __syncthreads();
  for (int o = 1; o < 256; o <<= 1) {
    int t = (tid >= o) ? sh[tid - o] : 0;
    __syncthreads();
    sh[tid] += t;
    __syncthreads();
  }
  boff[tid] = sh[tid] - v;  // exclusive
}

__global__ void k_scan3(const int* __restrict__ deg, const int* __restrict__ boff,
                        int* __restrict__ offs, int* __restrict__ csr) {
  __shared__ int sh[256];
  int tid = threadIdx.x;
  int n = blockIdx.x * 256 + tid;
  int v = (n < NND) ? deg[n] : 0;
  sh[tid] = v;
  __syncthreads();
  for (int o = 1; o < 256; o <<= 1) {
    int t2 = (tid >= o) ? sh[tid - o] : 0;
    __syncthreads();
    sh[tid] += t2;
    __syncthreads();
  }
  if (n < NND) {
    int x = boff[blockIdx.x] + sh[tid] - v;  // exclusive global offset
    offs[n] = x;
    csr[x] = n;   // slot 0 = self-loop
  }
}

// atomic-free scatter; 2 dst-range passes keep the csr write window L2-resident
__global__ void k_scatter(const int* __restrict__ ei, const int* __restrict__ offs,
                          const int* __restrict__ rank, int* __restrict__ csr,
                          int lo, int hi) {
  int e = blockIdx.x * 256 + threadIdx.x;
  if (e < NE) {
    int d = ei[NE + e];
    if (d >= lo && d < hi) csr[offs[d] + rank[e]] = ei[e];
  }
}

// x_seq [T][N][3] f32 -> xs2 [N][T] uint2 (4 bf16: x0,x1,x2,pad, pre-scaled by dinv)
__global__ void k_xsb(const float* __restrict__ x, const float* __restrict__ dinv,
                      uint2* __restrict__ xs2) {
  int g = blockIdx.x * 256 + threadIdx.x;
  if (g >= NND * TT) return;
  int n = g >> 3, t = g & 7;
  const float* xx = x + ((size_t)t * NND + n) * 3;
  float dn = dinv[n];
  xs2[(size_t)n * 8 + t] = make_uint2(pkbf(xx[0] * dn, xx[1] * dn),
                                      pkbf(xx[2] * dn, 0.f));
}

// ---------------- fused layer 1: aggregate + W1 + ReLU + fp8 pack ----------------

// thread (n, tp): tp = t-pair. uint4 gather = both timesteps per 16B load.
__global__ void k_yh1(const int* __restrict__ offs, const int* __restrict__ deg,
                      const int* __restrict__ csr, const uint4* __restrict__ xs4,
                      const float* __restrict__ dinv, const float* __restrict__ W1,
                      const float* __restrict__ b1, uint4* __restrict__ h1w) {
  int g = blockIdx.x * 256 + threadIdx.x;
  int n = g >> 2, tp = g & 3;
  if (n >= NND) return;
  int o0 = offs[n], d = deg[n];
  float a0 = 0.f, a1 = 0.f, a2 = 0.f;   // t = 2tp
  float c0 = 0.f, c1 = 0.f, c2 = 0.f;   // t = 2tp+1
  int i = 0;
  for (; i + 4 <= d; i += 4) {
    int s0 = csr[o0 + i], s1 = csr[o0 + i + 1];
    int s2 = csr[o0 + i + 2], s3 = csr[o0 + i + 3];
    uint4 u0 = xs4[(size_t)s0 * 4 + tp];
    uint4 u1 = xs4[(size_t)s1 * 4 + tp];
    uint4 u2 = xs4[(size_t)s2 * 4 + tp];
    uint4 u3 = xs4[(size_t)s3 * 4 + tp];
    a0 += bl(u0.x) + bl(u1.x) + bl(u2.x) + bl(u3.x);
    a1 += bh(u0.x) + bh(u1.x) + bh(u2.x) + bh(u3.x);
    a2 += bl(u0.y) + bl(u1.y) + bl(u2.y) + bl(u3.y);
    c0 += bl(u0.z) + bl(u1.z) + bl(u2.z) + bl(u3.z);
    c1 += bh(u0.z) + bh(u1.z) + bh(u2.z) + bh(u3.z);
    c2 += bl(u0.w) + bl(u1.w) + bl(u2.w) + bl(u3.w);
  }
  for (; i < d; ++i) {
    uint4 u = xs4[(size_t)csr[o0 + i] * 4 + tp];
    a0 += bl(u.x); a1 += bh(u.x); a2 += bl(u.y);
    c0 += bl(u.z); c1 += bh(u.z); c2 += bl(u.w);
  }
  float dn = dinv[n];
#pragma unroll
  for (int j = 0; j < 2; ++j) {
    float y0 = (j ? c0 : a0) * dn, y1 = (j ? c1 : a1) * dn, y2 = (j ? c2 : a2) * dn;
    size_t base = ((size_t)(2 * tp + j) * NND + n) * 4;
#pragma unroll
    for (int k = 0; k < 4; ++k) {
      float vv[16];
#pragma unroll
      for (int m = 0; m < 16; ++m) {
        int c = k * 16 + m;
        float hv = fmaf(y2, W1[128 + c], fmaf(y1, W1[64 + c], fmaf(y0, W1[c], b1[c])));
        vv[m] = fmaxf(hv, 0.f) * dn;
      }
      uint4 o;
      o.x = pk4_fp8(vv[0], vv[1], vv[2], vv[3]);
      o.y = pk4_fp8(vv[4], vv[5], vv[6], vv[7]);
      o.z = pk4_fp8(vv[8], vv[9], vv[10], vv[11]);
      o.w = pk4_fp8(vv[12], vv[13], vv[14], vv[15]);
      h1w[base + k] = o;
    }
  }
}

// ---------------- fused layer 2: gather + W2 GEMM + relu + pool ----------------

// packed converts + packed adds: 1 VALU instr/value
#define ACCPK(u) do { \
  acc2[0] += cvtpk2<false>((u).x); acc2[1] += cvtpk2<true>((u).x); \
  acc2[2] += cvtpk2<false>((u).y); acc2[3] += cvtpk2<true>((u).y); \
  acc2[4] += cvtpk2<false>((u).z); acc2[5] += cvtpk2<true>((u).z); \
  acc2[6] += cvtpk2<false>((u).w); acc2[7] += cvtpk2<true>((u).w); \
} while (0)

// XCD-pinned (t = blockIdx.x & 7): FETCH 266->50MB (round-11). bf16 As2 tile
// keeps block LDS at 25.6KB -> 6 blocks/CU by LDS. NO min-occupancy bound:
// round-12's __launch_bounds__(256,6) capped VGPR at 40 -> the gather loop
// (16 uint4-load regs + 16 acc regs) spilled ~45 dwords/thread to scratch ->
// WRITE_SIZE 1.5->287MB, FETCH 50->375MB, kernel went HBM-bound (229us).
// Plain bounds: compiler picks ~52-64 VGPR (no spill), LDS still allows 6/CU.
__launch_bounds__(256)
__global__ void k_l2f(const int* __restrict__ offs, const int* __restrict__ deg,
                      const int* __restrict__ csr, const uint4* __restrict__ h1all,
                      const float* __restrict__ dinv, const float* __restrict__ W2,
                      const float* __restrict__ b2, float* __restrict__ ppool) {
  __shared__ unsigned int As2[64 * 34];  // 8.7 KB, bf16 pairs, stride 34 uints
  __shared__ float Ws[64 * 64];          // 16 KB, W2^T, chunk-swizzled
  __shared__ float pool[64];
  int tid = threadIdx.x;
  int t = blockIdx.x & 7;
  int rows0 = (blockIdx.x >> 3) * 64;
  const uint4* h1v = h1all + (size_t)t * NND * 4;
  if (tid < 64) pool[tid] = 0.f;
  // Ws[j][swz(k)] = W2[k][j]
  for (int i = 0; i < 16; ++i) {
    int idx = i * 256 + tid;
    int k = idx >> 6, j = idx & 63;
    Ws[j * 64 + (((k >> 2) ^ ((j >> 3) & 7)) << 2) + (k & 3)] = W2[idx];
  }

  // ---- phase 1: gather (node row = tid>>2, q = tid&3 -> k = q*16+m) ----
  int row = tid >> 2, q = tid & 3;
  int n = rows0 + row;
  f32x2 acc2[8];
#pragma unroll
  for (int m = 0; m < 8; ++m) acc2[m] = (f32x2)(0.f);
  if (n < NND) {
    int o0 = offs[n], d = deg[n];
    int i = 0;
    for (; i + 4 <= d; i += 4) {
      int s0 = csr[o0 + i], s1 = csr[o0 + i + 1];
      int s2 = csr[o0 + i + 2], s3 = csr[o0 + i + 3];
      uint4 u0 = h1v[(size_t)s0 * 4 + q];
      uint4 u1 = h1v[(size_t)s1 * 4 + q];
      uint4 u2 = h1v[(size_t)s2 * 4 + q];
      uint4 u3 = h1v[(size_t)s3 * 4 + q];
      ACCPK(u0); ACCPK(u1); ACCPK(u2); ACCPK(u3);
    }
    for (; i < d; ++i) {
      uint4 u = h1v[(size_t)csr[o0 + i] * 4 + q];
      ACCPK(u);
    }
  }
  float dn = (n < NND) ? dinv[n] : 0.f;
  // pack 16 f32 -> 8 uints (bf16 pairs), store as 4x uint2 (8B aligned: 136%8=0)
#pragma unroll
  for (int j = 0; j < 4; ++j) {
    uint2 s;
    s.x = pkbf(acc2[2 * j].x * dn, acc2[2 * j].y * dn);
    s.y = pkbf(acc2[2 * j + 1].x * dn, acc2[2 * j + 1].y * dn);
    *(uint2*)&As2[row * 34 + q * 8 + j * 2] = s;
  }
  __syncthreads();

  // ---- phase 2: As[64,64](bf16) @ W2 -> relu+bias -> pool ----
  int rowg = tid >> 3, colg = tid & 7;
  int r0 = rowg * 2, c0 = colg * 8;
  float gac[2][8];
  for (int a = 0; a < 2; ++a)
    for (int b = 0; b < 8; ++b) gac[a][b] = 0.f;
  for (int k4 = 0; k4 < 16; ++k4) {
    float4 w[8];
    for (int cc = 0; cc < 8; ++cc)
      w[cc] = *(const float4*)&Ws[(c0 + cc) * 64 + ((k4 ^ colg) << 2)];
    for (int rr = 0; rr < 2; ++rr) {
      int r = r0 + rr;
      uint2 ab = *(const uint2*)&As2[r * 34 + k4 * 2];
      float4 av = make_float4(bl(ab.x), bh(ab.x), bl(ab.y), bh(ab.y));
      for (int cc = 0; cc < 8; ++cc) {
        gac[rr][cc] += av.x * w[cc].x;
        gac[rr][cc] += av.y * w[cc].y;
        gac[rr][cc] += av.z * w[cc].z;
        gac[rr][cc] += av.w * w[cc].w;
      }
    }
  }

  float b2c[8];
  for (int cc = 0; cc < 8; ++cc) b2c[cc] = b2[c0 + cc];
  float csum[8];
  for (int cc = 0; cc < 8; ++cc) csum[cc] = 0.f;
  for (int rr = 0; rr < 2; ++rr) {
    if (rows0 + r0 + rr < NND) {
      for (int cc = 0; cc < 8; ++cc)
        csum[cc] += fmaxf(gac[rr][cc] + b2c[cc], 0.f);
    }
  }
  for (int cc = 0; cc < 8; ++cc) atomicAdd(&pool[c0 + cc], csum[cc]);
  __syncthreads();
  if (tid < 64) atomicAdd(&ppool[t * 64 + tid], pool[tid]);
}

// ---------------- GRU + fc ----------------

__global__ void k_twih(const float* __restrict__ w, float* __restrict__ wt) {
  int g = blockIdx.x * 256 + threadIdx.x;
  if (g < 384 * 64) { int r = g >> 6, k = g & 63; wt[k * 384 + r] = w[g]; }
}
__global__ void k_twhh(const float* __restrict__ w, float* __restrict__ wt) {
  int g = blockIdx.x * 256 + threadIdx.x;
  if (g < 384 * 128) { int r = g >> 7, k = g & 127; wt[k * 384 + r] = w[g]; }
}

__launch_bounds__(384, 2)
__global__ void k_gru(const float* __restrict__ ppool, const float* __restrict__ wihT,
                      const float* __restrict__ whhT, const float* __restrict__ b_ih,
                      const float* __restrict__ b_hh, const float* __restrict__ fc_w,
                      const float* __restrict__ fc_b, float* __restrict__ out) {
  __shared__ float x[64], h[128], gi_s[384], gh_s[384], red[128];
  int j = threadIdx.x;  // 0..383
  float wih[64];
#pragma unroll
  for (int k = 0; k < 64; ++k) wih[k] = wihT[k * 384 + j];
  float whh[128];
#pragma unroll
  for (int k = 0; k < 128; ++k) whh[k] = whhT[k * 384 + j];
  float bi = b_ih[j], bh2 = b_hh[j];
  if (j < 128) h[j] = 0.f;
  const float invn = 1.0f / (float)NND;
  for (int t = 0; t < TT; ++t) {
    if (j < 64) x[j] = ppool[t * 64 + j] * invn;
    __syncthreads();
    float gi = bi, gh = bh2;
#pragma unroll
    for (int k4 = 0; k4 < 16; ++k4) {
      float4 xv = *(const float4*)&x[k4 * 4];
      gi = fmaf(wih[k4 * 4 + 0], xv.x, gi);
      gi = fmaf(wih[k4 * 4 + 1], xv.y, gi);
      gi = fmaf(wih[k4 * 4 + 2], xv.z, gi);
      gi = fmaf(wih[k4 * 4 + 3], xv.w, gi);
    }
#pragma unroll
    for (int k4 = 0; k4 < 32; ++k4) {
      float4 hv = *(const float4*)&h[k4 * 4];
      gh = fmaf(whh[k4 * 4 + 0], hv.x, gh);
      gh = fmaf(whh[k4 * 4 + 1], hv.y, gh);
      gh = fmaf(whh[k4 * 4 + 2], hv.z, gh);
      gh = fmaf(whh[k4 * 4 + 3], hv.w, gh);
    }
    gi_s[j] = gi;
    gh_s[j] = gh;
    __syncthreads();
    if (j < 128) {
      float r = 1.f / (1.f + expf(-(gi_s[j] + gh_s[j])));
      float z = 1.f / (1.f + expf(-(gi_s[128 + j] + gh_s[128 + j])));
      float nn = tanhf(gi_s[256 + j] + r * gh_s[256 + j]);
      h[j] = (1.f - z) * nn + z * h[j];
    }
    __syncthreads();
  }
  if (j < 128) red[j] = h[j] * fc_w[j];
  __syncthreads();
  for (int o = 64; o > 0; o >>= 1) {
    if (j < o) red[j] += red[j + o];
    __syncthreads();
  }
  if (j == 0) out[0] = red[0] + fc_b[0];
}

// ---------------- launch ----------------

extern "C" void kernel_launch(void* const* d_in, const int* in_sizes, int n_in,
                              void* d_out, int out_size, void* d_ws, size_t ws_size,
                              hipStream_t stream) {
  const float* x_seq = (const float*)d_in[0];
  const int*   ei    = (const int*)d_in[1];
  const float* W1    = (const float*)d_in[2];
  const float* b1    = (const float*)d_in[3];
  const float* W2    = (const float*)d_in[4];
  const float* b2    = (const float*)d_in[5];
  const float* w_ih  = (const float*)d_in[6];
  const float* w_hh  = (const float*)d_in[7];
  const float* b_ih  = (const float*)d_in[8];
  const float* b_hh  = (const float*)d_in[9];
  const float* fc_w  = (const float*)d_in[10];
  const float* fc_b  = (const float*)d_in[11];
  float* out = (float*)d_out;

  char* p = (char*)d_ws;
  size_t off = 0;
  auto carve = [&](size_t bytes) -> char* {
    char* q = p + off;
    off += (bytes + 255) & ~(size_t)255;
    return q;
  };
  int*   deg    = (int*)carve((size_t)NND * 4);
  float* dinv   = (float*)carve((size_t)NND * 4);
  int*   offs   = (int*)carve((size_t)NND * 4);
  int*   bsum   = (int*)carve(256 * 4);
  int*   boff   = (int*)carve(256 * 4);
  int*   csr    = (int*)carve((size_t)(NE + NND) * 4);
  uint2* xs2    = (uint2*)carve((size_t)NND * 8 * 8);        // 3.2 MB
  float* ppool  = (float*)carve((size_t)TT * 64 * 4);
  float* wihT   = (float*)carve((size_t)384 * 64 * 4);
  float* whhT   = (float*)carve((size_t)384 * 128 * 4);
  char*  tail   = carve((size_t)TT * NND * 64);              // 25.6 MB: h1all
  uint4* h1all  = (uint4*)tail;
  int*   rank   = (int*)tail;   // alias: rank dead before h1all's first write

  k_init<<<NBS, 256, 0, stream>>>(deg, ppool);
  k_deg<<<(NE + 255) / 256, 256, 0, stream>>>(ei, deg, rank);
  k_dinv<<<NBS, 256, 0, stream>>>(deg, dinv);
  k_scan1<<<NBS, 256, 0, stream>>>(deg, bsum);
  k_scan2<<<1, 256, 0, stream>>>(bsum, boff);
  k_scan3<<<NBS, 256, 0, stream>>>(deg, boff, offs, csr);
  // 2 atomic-free dst-range passes (csr window ~3.3MB, L2-resident)
  for (int pp = 0; pp < 2; ++pp) {
    int lo = pp * (NND / 2), hi = (pp == 1) ? NND : (NND / 2);
    k_scatter<<<(NE + 255) / 256, 256, 0, stream>>>(ei, offs, rank, csr, lo, hi);
  }
  k_xsb<<<(NND * TT + 255) / 256, 256, 0, stream>>>(x_seq, dinv, xs2);
  k_twih<<<(384 * 64 + 255) / 256, 256, 0, stream>>>(w_ih, wihT);
  k_twhh<<<(384 * 128 + 255) / 256, 256, 0, stream>>>(w_hh, whhT);
  // fused layer-1, all t (rank dead from here; h1all reuses its space)
  k_yh1<<<(NND * 4 + 255) / 256, 256, 0, stream>>>(offs, deg, csr,
                                                   (const uint4*)xs2, dinv,
                                                   W1, b1, h1all);
  // fused layer-2 + pool, ALL t, XCD-pinned t-slices
  k_l2f<<<TT * NBT2, 256, 0, stream>>>(offs, deg, csr, h1all, dinv, W2, b2, ppool);

  k_gru<<<1, 384, 0, stream>>>(ppool, wihT, whhT, b_ih, b_hh, fc_w, fc_b, out);
}

// Round 14
// 378.023 us; speedup vs baseline: 1.2216x; 1.0375x over previous
//
#include <hip/hip_runtime.h>
#include <hip/hip_fp8.h>
#include <hip/hip_bf16.h>

#define NND 50000
#define NE  1600000
#define TT  8
#define NBS ((NND + 255) / 256)   // 196 blocks over nodes
#define NBT2 ((NND + 63) / 64)    // 782 64-node tiles

typedef __attribute__((ext_vector_type(2))) float f32x2;
typedef __attribute__((ext_vector_type(4))) float f32x4;
typedef __attribute__((ext_vector_type(8))) short bf16x8;   // 8 bf16 = 4 VGPR

// ---------------- fp8 / bf16 helpers ----------------

template <int I>
__device__ inline float fp8tof(unsigned int u) {
#if __has_builtin(__builtin_amdgcn_cvt_f32_fp8)
  return __builtin_amdgcn_cvt_f32_fp8(u, I);   // byte-select must be literal
#else
  __hip_fp8_e4m3 v; v.__x = (unsigned char)(u >> (I * 8)); return (float)v;
#endif
}

// packed: 2 fp8 -> 2 f32 in one instruction (word W: bytes 2W,2W+1 -> x,y)
template <bool W>
__device__ inline f32x2 cvtpk2(unsigned int u) {
#if __has_builtin(__builtin_amdgcn_cvt_pk_f32_fp8)
  return __builtin_amdgcn_cvt_pk_f32_fp8(u, W);
#else
  f32x2 r;
  r.x = fp8tof<W ? 2 : 0>(u);
  r.y = fp8tof<W ? 3 : 1>(u);
  return r;
#endif
}

__device__ inline unsigned int pk4_fp8(float a, float b, float c, float d) {
#if __has_builtin(__builtin_amdgcn_cvt_pk_fp8_f32)
  int v = 0;
  v = __builtin_amdgcn_cvt_pk_fp8_f32(a, b, v, false);  // bytes 0,1
  v = __builtin_amdgcn_cvt_pk_fp8_f32(c, d, v, true);   // bytes 2,3
  return (unsigned int)v;
#else
  __hip_fp8_e4m3 qa(a), qb(b), qc(c), qd(d);
  return (unsigned int)qa.__x | ((unsigned int)qb.__x << 8) |
         ((unsigned int)qc.__x << 16) | ((unsigned int)qd.__x << 24);
#endif
}

__device__ inline unsigned int pkbf(float a, float b) {
  __hip_bfloat16 ha = __float2bfloat16(a), hb = __float2bfloat16(b);
  unsigned short ua = *(unsigned short*)&ha, ub = *(unsigned short*)&hb;
  return (unsigned int)ua | ((unsigned int)ub << 16);
}
__device__ inline float bl(unsigned int w) { return __uint_as_float(w << 16); }
__device__ inline float bh(unsigned int w) { return __uint_as_float(w & 0xffff0000u); }

// ---------------- preprocessing ----------------

__global__ void k_init(int* __restrict__ deg, float* __restrict__ ppool) {
  int i = blockIdx.x * 256 + threadIdx.x;
  if (i < NND) deg[i] = 1;              // self-loop
  if (i < TT * 64) ppool[i] = 0.f;
}

// degree histogram; atomic old-value = unique slot rank (>=1; slot 0 = self-loop)
__global__ void k_deg(const int* __restrict__ ei, int* __restrict__ deg,
                      int* __restrict__ rank) {
  int e = blockIdx.x * 256 + threadIdx.x;
  if (e < NE) rank[e] = atomicAdd(&deg[ei[NE + e]], 1);
}

__global__ void k_dinv(const int* __restrict__ deg, float* __restrict__ dinv) {
  int n = blockIdx.x * 256 + threadIdx.x;
  if (n < NND) dinv[n] = rsqrtf((float)deg[n]);
}

__global__ void k_scan1(const int* __restrict__ deg, int* __restrict__ bsum) {
  __shared__ int sh[256];
  int n = blockIdx.x * 256 + threadIdx.x;
  sh[threadIdx.x] = (n < NND) ? deg[n] : 0;
  __syncthreads();
  for (int o = 128; o > 0; o >>= 1) {
    if (threadIdx.x < o) sh[threadIdx.x] += sh[threadIdx.x + o];
    __syncthreads();
  }
  if (threadIdx.x == 0) bsum[blockIdx.x] = sh[0];
}

__global__ void k_scan2(const int* __restrict__ bsum, int* __restrict__ boff) {
  __shared__ int sh[256];
  int tid = threadIdx.x;
  int v = (tid < NBS) ? bsum[tid] : 0;
  sh[tid] = v;
  __syncthreads();
  for (int o = 1; o < 256; o <<= 1) {
    int t = (tid >= o) ? sh[tid - o] : 0;
    __syncthreads();
    sh[tid] += t;
    __syncthreads();
  }
  boff[tid] = sh[tid] - v;  // exclusive
}

__global__ void k_scan3(const int* __restrict__ deg, const int* __restrict__ boff,
                        int* __restrict__ offs, int* __restrict__ csr) {
  __shared__ int sh[256];
  int tid = threadIdx.x;
  int n = blockIdx.x * 256 + tid;
  int v = (n < NND) ? deg[n] : 0;
  sh[tid] = v;
  __syncthreads();
  for (int o = 1; o < 256; o <<= 1) {
    int t2 = (tid >= o) ? sh[tid - o] : 0;
    __syncthreads();
    sh[tid] += t2;
    __syncthreads();
  }
  if (n < NND) {
    int x = boff[blockIdx.x] + sh[tid] - v;  // exclusive global offset
    offs[n] = x;
    csr[x] = n;   // slot 0 = self-loop
  }
}

// atomic-free scatter; 2 dst-range passes keep the csr write window L2-resident
__global__ void k_scatter(const int* __restrict__ ei, const int* __restrict__ offs,
                          const int* __restrict__ rank, int* __restrict__ csr,
                          int lo, int hi) {
  int e = blockIdx.x * 256 + threadIdx.x;
  if (e < NE) {
    int d = ei[NE + e];
    if (d >= lo && d < hi) csr[offs[d] + rank[e]] = ei[e];
  }
}

// x_seq [T][N][3] f32 -> xs2 [N][T] uint2 (4 bf16: x0,x1,x2,pad, pre-scaled by dinv)
__global__ void k_xsb(const float* __restrict__ x, const float* __restrict__ dinv,
                      uint2* __restrict__ xs2) {
  int g = blockIdx.x * 256 + threadIdx.x;
  if (g >= NND * TT) return;
  int n = g >> 3, t = g & 7;
  const float* xx = x + ((size_t)t * NND + n) * 3;
  float dn = dinv[n];
  xs2[(size_t)n * 8 + t] = make_uint2(pkbf(xx[0] * dn, xx[1] * dn),
                                      pkbf(xx[2] * dn, 0.f));
}

// ---------------- fused layer 1: aggregate + W1 + ReLU + fp8 pack ----------------

// thread (n, tp): tp = t-pair. uint4 gather = both timesteps per 16B load.
__global__ void k_yh1(const int* __restrict__ offs, const int* __restrict__ deg,
                      const int* __restrict__ csr, const uint4* __restrict__ xs4,
                      const float* __restrict__ dinv, const float* __restrict__ W1,
                      const float* __restrict__ b1, uint4* __restrict__ h1w) {
  int g = blockIdx.x * 256 + threadIdx.x;
  int n = g >> 2, tp = g & 3;
  if (n >= NND) return;
  int o0 = offs[n], d = deg[n];
  float a0 = 0.f, a1 = 0.f, a2 = 0.f;   // t = 2tp
  float c0 = 0.f, c1 = 0.f, c2 = 0.f;   // t = 2tp+1
  int i = 0;
  for (; i + 4 <= d; i += 4) {
    int s0 = csr[o0 + i], s1 = csr[o0 + i + 1];
    int s2 = csr[o0 + i + 2], s3 = csr[o0 + i + 3];
    uint4 u0 = xs4[(size_t)s0 * 4 + tp];
    uint4 u1 = xs4[(size_t)s1 * 4 + tp];
    uint4 u2 = xs4[(size_t)s2 * 4 + tp];
    uint4 u3 = xs4[(size_t)s3 * 4 + tp];
    a0 += bl(u0.x) + bl(u1.x) + bl(u2.x) + bl(u3.x);
    a1 += bh(u0.x) + bh(u1.x) + bh(u2.x) + bh(u3.x);
    a2 += bl(u0.y) + bl(u1.y) + bl(u2.y) + bl(u3.y);
    c0 += bl(u0.z) + bl(u1.z) + bl(u2.z) + bl(u3.z);
    c1 += bh(u0.z) + bh(u1.z) + bh(u2.z) + bh(u3.z);
    c2 += bl(u0.w) + bl(u1.w) + bl(u2.w) + bl(u3.w);
  }
  for (; i < d; ++i) {
    uint4 u = xs4[(size_t)csr[o0 + i] * 4 + tp];
    a0 += bl(u.x); a1 += bh(u.x); a2 += bl(u.y);
    c0 += bl(u.z); c1 += bh(u.z); c2 += bl(u.w);
  }
  float dn = dinv[n];
#pragma unroll
  for (int j = 0; j < 2; ++j) {
    float y0 = (j ? c0 : a0) * dn, y1 = (j ? c1 : a1) * dn, y2 = (j ? c2 : a2) * dn;
    size_t base = ((size_t)(2 * tp + j) * NND + n) * 4;
#pragma unroll
    for (int k = 0; k < 4; ++k) {
      float vv[16];
#pragma unroll
      for (int m = 0; m < 16; ++m) {
        int c = k * 16 + m;
        float hv = fmaf(y2, W1[128 + c], fmaf(y1, W1[64 + c], fmaf(y0, W1[c], b1[c])));
        vv[m] = fmaxf(hv, 0.f) * dn;
      }
      uint4 o;
      o.x = pk4_fp8(vv[0], vv[1], vv[2], vv[3]);
      o.y = pk4_fp8(vv[4], vv[5], vv[6], vv[7]);
      o.z = pk4_fp8(vv[8], vv[9], vv[10], vv[11]);
      o.w = pk4_fp8(vv[12], vv[13], vv[14], vv[15]);
      h1w[base + k] = o;
    }
  }
}

// ---------------- fused layer 2: gather + MFMA GEMM + relu + pool ----------------

// packed converts + packed adds: 1 VALU instr/value
#define ACCPK(u) do { \
  acc2[0] += cvtpk2<false>((u).x); acc2[1] += cvtpk2<true>((u).x); \
  acc2[2] += cvtpk2<false>((u).y); acc2[3] += cvtpk2<true>((u).y); \
  acc2[4] += cvtpk2<false>((u).z); acc2[5] += cvtpk2<true>((u).z); \
  acc2[6] += cvtpk2<false>((u).w); acc2[7] += cvtpk2<true>((u).w); \
} while (0)

// XCD-pinned (t = blockIdx.x & 7): FETCH 266->50MB. Phase-2 GEMM now on the
// MATRIX cores: As (bf16, stride 36 uints = 16B-aligned frags, 2-way banks)
// @ W2^T (bf16) via mfma_f32_16x16x32_bf16 — replaces 1024 f32 FMA/thread
// (~21-25us dense on VALU, MfmaUtil was 0.0 all session). Fragment layouts:
// A: row=l&15, k=(l>>4)*8+j; B(from W2^T): col=l&15, same k; C/D: col=lane&15,
// row=(lane>>4)*4+r [m89-verified]. LDS 18.9KB -> 8 blocks/CU by LDS.
// No min-occupancy bound (round-12 lesson: forced VGPR cap -> 287MB spill).
__launch_bounds__(256)
__global__ void k_l2f(const int* __restrict__ offs, const int* __restrict__ deg,
                      const int* __restrict__ csr, const uint4* __restrict__ h1all,
                      const float* __restrict__ dinv, const float* __restrict__ W2,
                      const float* __restrict__ b2, float* __restrict__ ppool) {
  __shared__ __align__(16) unsigned int As2[64 * 36];  // 9.2 KB bf16 pairs
  __shared__ __align__(16) unsigned int WsT[64 * 36];  // 9.2 KB W2^T bf16 pairs
  __shared__ float pool[64];
  int tid = threadIdx.x;
  int t = blockIdx.x & 7;
  int rows0 = (blockIdx.x >> 3) * 64;
  const uint4* h1v = h1all + (size_t)t * NND * 4;
  if (tid < 64) pool[tid] = 0.f;
  // WsT[j][k] = bf16(W2[k][j]); uint j*36+k2 = pair (k=2k2, 2k2+1)
  for (int i = 0; i < 8; ++i) {
    int p2 = i * 256 + tid;           // [0, 2048)
    int j = p2 >> 5, k2 = p2 & 31;
    WsT[j * 36 + k2] = pkbf(W2[(2 * k2) * 64 + j], W2[(2 * k2 + 1) * 64 + j]);
  }

  // ---- phase 1: gather (node row = tid>>2, q = tid&3 -> k = q*16+m) ----
  int row = tid >> 2, q = tid & 3;
  int n = rows0 + row;
  f32x2 acc2[8];
#pragma unroll
  for (int m = 0; m < 8; ++m) acc2[m] = (f32x2)(0.f);
  if (n < NND) {
    int o0 = offs[n], d = deg[n];
    int i = 0;
    for (; i + 4 <= d; i += 4) {
      int s0 = csr[o0 + i], s1 = csr[o0 + i + 1];
      int s2 = csr[o0 + i + 2], s3 = csr[o0 + i + 3];
      uint4 u0 = h1v[(size_t)s0 * 4 + q];
      uint4 u1 = h1v[(size_t)s1 * 4 + q];
      uint4 u2 = h1v[(size_t)s2 * 4 + q];
      uint4 u3 = h1v[(size_t)s3 * 4 + q];
      ACCPK(u0); ACCPK(u1); ACCPK(u2); ACCPK(u3);
    }
    for (; i < d; ++i) {
      uint4 u = h1v[(size_t)csr[o0 + i] * 4 + q];
      ACCPK(u);
    }
  }
  float dn = (n < NND) ? dinv[n] : 0.f;
  // pack 16 f32 -> 8 uints (bf16 pairs); uint u=q*8+j*2 holds k=2u,2u+1
#pragma unroll
  for (int j = 0; j < 4; ++j) {
    uint2 s;
    s.x = pkbf(acc2[2 * j].x * dn, acc2[2 * j].y * dn);
    s.y = pkbf(acc2[2 * j + 1].x * dn, acc2[2 * j + 1].y * dn);
    *(uint2*)&As2[row * 36 + q * 8 + j * 2] = s;
  }
  __syncthreads();

  // ---- phase 2: MFMA. wave w: rows 16w..16w+15; 4 col-tiles x 2 K-steps ----
  int w = tid >> 6, l = tid & 63;
  int lr = l & 15, lg = l >> 4;
  f32x4 dacc[4];
#pragma unroll
  for (int ct = 0; ct < 4; ++ct) dacc[ct] = (f32x4)(0.f);
#pragma unroll
  for (int kk = 0; kk < 2; ++kk) {
    // A-frag: row 16w+lr, k = kk*32 + lg*8 + j  -> uint off kk*16 + lg*4
    bf16x8 af = *(const bf16x8*)&As2[(16 * w + lr) * 36 + kk * 16 + lg * 4];
#pragma unroll
    for (int ct = 0; ct < 4; ++ct) {
      bf16x8 bf = *(const bf16x8*)&WsT[(ct * 16 + lr) * 36 + kk * 16 + lg * 4];
      dacc[ct] = __builtin_amdgcn_mfma_f32_16x16x32_bf16(af, bf, dacc[ct], 0, 0, 0);
    }
  }
  // epilogue: D row = 16w + lg*4 + r, col = ct*16 + lr. relu+bias, row-sum.
  int growbase = rows0 + 16 * w + lg * 4;
#pragma unroll
  for (int ct = 0; ct < 4; ++ct) {
    float bb = b2[ct * 16 + lr];
    float s = 0.f;
#pragma unroll
    for (int r = 0; r < 4; ++r)
      if (growbase + r < NND) s += fmaxf(dacc[ct][r] + bb, 0.f);
    s += __shfl_xor(s, 16);
    s += __shfl_xor(s, 32);
    if (l < 16) atomicAdd(&pool[ct * 16 + lr], s);
  }
  __syncthreads();
  if (tid < 64) atomicAdd(&ppool[t * 64 + tid], pool[tid]);
}

// ---------------- GRU + fc ----------------

__global__ void k_twih(const float* __restrict__ w, float* __restrict__ wt) {
  int g = blockIdx.x * 256 + threadIdx.x;
  if (g < 384 * 64) { int r = g >> 6, k = g & 63; wt[k * 384 + r] = w[g]; }
}
__global__ void k_twhh(const float* __restrict__ w, float* __restrict__ wt) {
  int g = blockIdx.x * 256 + threadIdx.x;
  if (g < 384 * 128) { int r = g >> 7, k = g & 127; wt[k * 384 + r] = w[g]; }
}

__launch_bounds__(384, 2)
__global__ void k_gru(const float* __restrict__ ppool, const float* __restrict__ wihT,
                      const float* __restrict__ whhT, const float* __restrict__ b_ih,
                      const float* __restrict__ b_hh, const float* __restrict__ fc_w,
                      const float* __restrict__ fc_b, float* __restrict__ out) {
  __shared__ float x[64], h[128], gi_s[384], gh_s[384], red[128];
  int j = threadIdx.x;  // 0..383
  float wih[64];
#pragma unroll
  for (int k = 0; k < 64; ++k) wih[k] = wihT[k * 384 + j];
  float whh[128];
#pragma unroll
  for (int k = 0; k < 128; ++k) whh[k] = whhT[k * 384 + j];
  float bi = b_ih[j], bh2 = b_hh[j];
  if (j < 128) h[j] = 0.f;
  const float invn = 1.0f / (float)NND;
  for (int t = 0; t < TT; ++t) {
    if (j < 64) x[j] = ppool[t * 64 + j] * invn;
    __syncthreads();
    float gi = bi, gh = bh2;
#pragma unroll
    for (int k4 = 0; k4 < 16; ++k4) {
      float4 xv = *(const float4*)&x[k4 * 4];
      gi = fmaf(wih[k4 * 4 + 0], xv.x, gi);
      gi = fmaf(wih[k4 * 4 + 1], xv.y, gi);
      gi = fmaf(wih[k4 * 4 + 2], xv.z, gi);
      gi = fmaf(wih[k4 * 4 + 3], xv.w, gi);
    }
#pragma unroll
    for (int k4 = 0; k4 < 32; ++k4) {
      float4 hv = *(const float4*)&h[k4 * 4];
      gh = fmaf(whh[k4 * 4 + 0], hv.x, gh);
      gh = fmaf(whh[k4 * 4 + 1], hv.y, gh);
      gh = fmaf(whh[k4 * 4 + 2], hv.z, gh);
      gh = fmaf(whh[k4 * 4 + 3], hv.w, gh);
    }
    gi_s[j] = gi;
    gh_s[j] = gh;
    __syncthreads();
    if (j < 128) {
      float r = 1.f / (1.f + expf(-(gi_s[j] + gh_s[j])));
      float z = 1.f / (1.f + expf(-(gi_s[128 + j] + gh_s[128 + j])));
      float nn = tanhf(gi_s[256 + j] + r * gh_s[256 + j]);
      h[j] = (1.f - z) * nn + z * h[j];
    }
    __syncthreads();
  }
  if (j < 128) red[j] = h[j] * fc_w[j];
  __syncthreads();
  for (int o = 64; o > 0; o >>= 1) {
    if (j < o) red[j] += red[j + o];
    __syncthreads();
  }
  if (j == 0) out[0] = red[0] + fc_b[0];
}

// ---------------- launch ----------------

extern "C" void kernel_launch(void* const* d_in, const int* in_sizes, int n_in,
                              void* d_out, int out_size, void* d_ws, size_t ws_size,
                              hipStream_t stream) {
  const float* x_seq = (const float*)d_in[0];
  const int*   ei    = (const int*)d_in[1];
  const float* W1    = (const float*)d_in[2];
  const float* b1    = (const float*)d_in[3];
  const float* W2    = (const float*)d_in[4];
  const float* b2    = (const float*)d_in[5];
  const float* w_ih  = (const float*)d_in[6];
  const float* w_hh  = (const float*)d_in[7];
  const float* b_ih  = (const float*)d_in[8];
  const float* b_hh  = (const float*)d_in[9];
  const float* fc_w  = (const float*)d_in[10];
  const float* fc_b  = (const float*)d_in[11];
  float* out = (float*)d_out;

  char* p = (char*)d_ws;
  size_t off = 0;
  auto carve = [&](size_t bytes) -> char* {
    char* q = p + off;
    off += (bytes + 255) & ~(size_t)255;
    return q;
  };
  int*   deg    = (int*)carve((size_t)NND * 4);
  float* dinv   = (float*)carve((size_t)NND * 4);
  int*   offs   = (int*)carve((size_t)NND * 4);
  int*   bsum   = (int*)carve(256 * 4);
  int*   boff   = (int*)carve(256 * 4);
  int*   csr    = (int*)carve((size_t)(NE + NND) * 4);
  uint2* xs2    = (uint2*)carve((size_t)NND * 8 * 8);        // 3.2 MB
  float* ppool  = (float*)carve((size_t)TT * 64 * 4);
  float* wihT   = (float*)carve((size_t)384 * 64 * 4);
  float* whhT   = (float*)carve((size_t)384 * 128 * 4);
  char*  tail   = carve((size_t)TT * NND * 64);              // 25.6 MB: h1all
  uint4* h1all  = (uint4*)tail;
  int*   rank   = (int*)tail;   // alias: rank dead before h1all's first write

  k_init<<<NBS, 256, 0, stream>>>(deg, ppool);
  k_deg<<<(NE + 255) / 256, 256, 0, stream>>>(ei, deg, rank);
  k_dinv<<<NBS, 256, 0, stream>>>(deg, dinv);
  k_scan1<<<NBS, 256, 0, stream>>>(deg, bsum);
  k_scan2<<<1, 256, 0, stream>>>(bsum, boff);
  k_scan3<<<NBS, 256, 0, stream>>>(deg, boff, offs, csr);
  // 2 atomic-free dst-range passes (csr window ~3.3MB, L2-resident)
  for (int pp = 0; pp < 2; ++pp) {
    int lo = pp * (NND / 2), hi = (pp == 1) ? NND : (NND / 2);
    k_scatter<<<(NE + 255) / 256, 256, 0, stream>>>(ei, offs, rank, csr, lo, hi);
  }
  k_xsb<<<(NND * TT + 255) / 256, 256, 0, stream>>>(x_seq, dinv, xs2);
  k_twih<<<(384 * 64 + 255) / 256, 256, 0, stream>>>(w_ih, wihT);
  k_twhh<<<(384 * 128 + 255) / 256, 256, 0, stream>>>(w_hh, whhT);
  // fused layer-1, all t (rank dead from here; h1all reuses its space)
  k_yh1<<<(NND * 4 + 255) / 256, 256, 0, stream>>>(offs, deg, csr,
                                                   (const uint4*)xs2, dinv,
                                                   W1, b1, h1all);
  // fused layer-2 + pool, ALL t, XCD-pinned t-slices, MFMA phase-2
  k_l2f<<<TT * NBT2, 256, 0, stream>>>(offs, deg, csr, h1all, dinv, W2, b2, ppool);

  k_gru<<<1, 384, 0, stream>>>(ppool, wihT, whhT, b_ih, b_hh, fc_w, fc_b, out);
}

// Round 15
// 366.367 us; speedup vs baseline: 1.2605x; 1.0318x over previous
//
#include <hip/hip_runtime.h>
#include <hip/hip_fp8.h>
#include <hip/hip_bf16.h>

#define NND 50000
#define NE  1600000
#define TT  8
#define NBS ((NND + 255) / 256)   // 196 blocks over nodes
#define NBT2 ((NND + 63) / 64)    // 782 64-node tiles

typedef __attribute__((ext_vector_type(2))) float f32x2;
typedef __attribute__((ext_vector_type(4))) float f32x4;
typedef __attribute__((ext_vector_type(8))) short bf16x8;   // 8 bf16 = 4 VGPR

// ---------------- fp8 / bf16 helpers ----------------

template <int I>
__device__ inline float fp8tof(unsigned int u) {
#if __has_builtin(__builtin_amdgcn_cvt_f32_fp8)
  return __builtin_amdgcn_cvt_f32_fp8(u, I);   // byte-select must be literal
#else
  __hip_fp8_e4m3 v; v.__x = (unsigned char)(u >> (I * 8)); return (float)v;
#endif
}

// packed: 2 fp8 -> 2 f32 in one instruction (word W: bytes 2W,2W+1 -> x,y)
template <bool W>
__device__ inline f32x2 cvtpk2(unsigned int u) {
#if __has_builtin(__builtin_amdgcn_cvt_pk_f32_fp8)
  return __builtin_amdgcn_cvt_pk_f32_fp8(u, W);
#else
  f32x2 r;
  r.x = fp8tof<W ? 2 : 0>(u);
  r.y = fp8tof<W ? 3 : 1>(u);
  return r;
#endif
}

__device__ inline unsigned int pk4_fp8(float a, float b, float c, float d) {
#if __has_builtin(__builtin_amdgcn_cvt_pk_fp8_f32)
  int v = 0;
  v = __builtin_amdgcn_cvt_pk_fp8_f32(a, b, v, false);  // bytes 0,1
  v = __builtin_amdgcn_cvt_pk_fp8_f32(c, d, v, true);   // bytes 2,3
  return (unsigned int)v;
#else
  __hip_fp8_e4m3 qa(a), qb(b), qc(c), qd(d);
  return (unsigned int)qa.__x | ((unsigned int)qb.__x << 8) |
         ((unsigned int)qc.__x << 16) | ((unsigned int)qd.__x << 24);
#endif
}

__device__ inline unsigned int pkbf(float a, float b) {
  __hip_bfloat16 ha = __float2bfloat16(a), hb = __float2bfloat16(b);
  unsigned short ua = *(unsigned short*)&ha, ub = *(unsigned short*)&hb;
  return (unsigned int)ua | ((unsigned int)ub << 16);
}
__device__ inline float bl(unsigned int w) { return __uint_as_float(w << 16); }
__device__ inline float bh(unsigned int w) { return __uint_as_float(w & 0xffff0000u); }

// ---------------- preprocessing ----------------

__global__ void k_init(int* __restrict__ deg, float* __restrict__ ppool) {
  int i = blockIdx.x * 256 + threadIdx.x;
  if (i < NND) deg[i] = 1;              // self-loop
  if (i < TT * 64) ppool[i] = 0.f;
}

// degree histogram; atomic old-value = unique slot rank (>=1; slot 0 = self-loop)
__global__ void k_deg(const int* __restrict__ ei, int* __restrict__ deg,
                      int* __restrict__ rank) {
  int e = blockIdx.x * 256 + threadIdx.x;
  if (e < NE) rank[e] = atomicAdd(&deg[ei[NE + e]], 1);
}

__global__ void k_dinv(const int* __restrict__ deg, float* __restrict__ dinv) {
  int n = blockIdx.x * 256 + threadIdx.x;
  if (n < NND) dinv[n] = rsqrtf((float)deg[n]);
}

__global__ void k_scan1(const int* __restrict__ deg, int* __restrict__ bsum) {
  __shared__ int sh[256];
  int n = blockIdx.x * 256 + threadIdx.x;
  sh[threadIdx.x] = (n < NND) ? deg[n] : 0;
  __syncthreads();
  for (int o = 128; o > 0; o >>= 1) {
    if (threadIdx.x < o) sh[threadIdx.x] += sh[threadIdx.x + o];
    __syncthreads();
  }
  if (threadIdx.x == 0) bsum[blockIdx.x] = sh[0];
}

__global__ void k_scan2(const int* __restrict__ bsum, int* __restrict__ boff) {
  __shared__ int sh[256];
  int tid = threadIdx.x;
  int v = (tid < NBS) ? bsum[tid] : 0;
  sh[tid] = v;
  __syncthreads();
  for (int o = 1; o < 256; o <<= 1) {
    int t = (tid >= o) ? sh[tid - o] : 0;
    __syncthreads();
    sh[tid] += t;
    __syncthreads();
  }
  boff[tid] = sh[tid] - v;  // exclusive
}

__global__ void k_scan3(const int* __restrict__ deg, const int* __restrict__ boff,
                        int* __restrict__ offs, int* __restrict__ csr) {
  __shared__ int sh[256];
  int tid = threadIdx.x;
  int n = blockIdx.x * 256 + tid;
  int v = (n < NND) ? deg[n] : 0;
  sh[tid] = v;
  __syncthreads();
  for (int o = 1; o < 256; o <<= 1) {
    int t2 = (tid >= o) ? sh[tid - o] : 0;
    __syncthreads();
    sh[tid] += t2;
    __syncthreads();
  }
  if (n < NND) {
    int x = boff[blockIdx.x] + sh[tid] - v;  // exclusive global offset
    offs[n] = x;
    csr[x] = n;   // slot 0 = self-loop
  }
}

// atomic-free scatter; 2 dst-range passes keep the csr write window L2-resident
__global__ void k_scatter(const int* __restrict__ ei, const int* __restrict__ offs,
                          const int* __restrict__ rank, int* __restrict__ csr,
                          int lo, int hi) {
  int e = blockIdx.x * 256 + threadIdx.x;
  if (e < NE) {
    int d = ei[NE + e];
    if (d >= lo && d < hi) csr[offs[d] + rank[e]] = ei[e];
  }
}

// x_seq [T][N][3] f32 -> xs2 [N][T] uint2 (4 bf16: x0,x1,x2,pad, pre-scaled by dinv)
__global__ void k_xsb(const float* __restrict__ x, const float* __restrict__ dinv,
                      uint2* __restrict__ xs2) {
  int g = blockIdx.x * 256 + threadIdx.x;
  if (g >= NND * TT) return;
  int n = g >> 3, t = g & 7;
  const float* xx = x + ((size_t)t * NND + n) * 3;
  float dn = dinv[n];
  xs2[(size_t)n * 8 + t] = make_uint2(pkbf(xx[0] * dn, xx[1] * dn),
                                      pkbf(xx[2] * dn, 0.f));
}

// ---------------- fused layer 1: aggregate + W1 + ReLU + fp8 pack ----------------

// thread (n, tp): tp = t-pair. uint4 gather = both timesteps per 16B load.
// Unroll-8: 8 index loads then 8 xs loads all in flight (latency-bound fix).
__global__ void k_yh1(const int* __restrict__ offs, const int* __restrict__ deg,
                      const int* __restrict__ csr, const uint4* __restrict__ xs4,
                      const float* __restrict__ dinv, const float* __restrict__ W1,
                      const float* __restrict__ b1, uint4* __restrict__ h1w) {
  int g = blockIdx.x * 256 + threadIdx.x;
  int n = g >> 2, tp = g & 3;
  if (n >= NND) return;
  int o0 = offs[n], d = deg[n];
  float a0 = 0.f, a1 = 0.f, a2 = 0.f;   // t = 2tp
  float c0 = 0.f, c1 = 0.f, c2 = 0.f;   // t = 2tp+1
  int i = 0;
  for (; i + 8 <= d; i += 8) {
    int s[8];
#pragma unroll
    for (int u = 0; u < 8; ++u) s[u] = csr[o0 + i + u];
    uint4 uu[8];
#pragma unroll
    for (int u = 0; u < 8; ++u) uu[u] = xs4[(size_t)s[u] * 4 + tp];
#pragma unroll
    for (int u = 0; u < 8; ++u) {
      a0 += bl(uu[u].x); a1 += bh(uu[u].x); a2 += bl(uu[u].y);
      c0 += bl(uu[u].z); c1 += bh(uu[u].z); c2 += bl(uu[u].w);
    }
  }
  for (; i + 4 <= d; i += 4) {
    int s[4];
#pragma unroll
    for (int u = 0; u < 4; ++u) s[u] = csr[o0 + i + u];
    uint4 uu[4];
#pragma unroll
    for (int u = 0; u < 4; ++u) uu[u] = xs4[(size_t)s[u] * 4 + tp];
#pragma unroll
    for (int u = 0; u < 4; ++u) {
      a0 += bl(uu[u].x); a1 += bh(uu[u].x); a2 += bl(uu[u].y);
      c0 += bl(uu[u].z); c1 += bh(uu[u].z); c2 += bl(uu[u].w);
    }
  }
  for (; i < d; ++i) {
    uint4 u = xs4[(size_t)csr[o0 + i] * 4 + tp];
    a0 += bl(u.x); a1 += bh(u.x); a2 += bl(u.y);
    c0 += bl(u.z); c1 += bh(u.z); c2 += bl(u.w);
  }
  float dn = dinv[n];
#pragma unroll
  for (int j = 0; j < 2; ++j) {
    float y0 = (j ? c0 : a0) * dn, y1 = (j ? c1 : a1) * dn, y2 = (j ? c2 : a2) * dn;
    size_t base = ((size_t)(2 * tp + j) * NND + n) * 4;
#pragma unroll
    for (int k = 0; k < 4; ++k) {
      float vv[16];
#pragma unroll
      for (int m = 0; m < 16; ++m) {
        int c = k * 16 + m;
        float hv = fmaf(y2, W1[128 + c], fmaf(y1, W1[64 + c], fmaf(y0, W1[c], b1[c])));
        vv[m] = fmaxf(hv, 0.f) * dn;
      }
      uint4 o;
      o.x = pk4_fp8(vv[0], vv[1], vv[2], vv[3]);
      o.y = pk4_fp8(vv[4], vv[5], vv[6], vv[7]);
      o.z = pk4_fp8(vv[8], vv[9], vv[10], vv[11]);
      o.w = pk4_fp8(vv[12], vv[13], vv[14], vv[15]);
      h1w[base + k] = o;
    }
  }
}

// ---------------- fused layer 2: gather + MFMA GEMM + relu + pool ----------------

// packed converts + packed adds: 1 VALU instr/value
#define ACCPK(u) do { \
  acc2[0] += cvtpk2<false>((u).x); acc2[1] += cvtpk2<true>((u).x); \
  acc2[2] += cvtpk2<false>((u).y); acc2[3] += cvtpk2<true>((u).y); \
  acc2[4] += cvtpk2<false>((u).z); acc2[5] += cvtpk2<true>((u).z); \
  acc2[6] += cvtpk2<false>((u).w); acc2[7] += cvtpk2<true>((u).w); \
} while (0)

// XCD-pinned (t = blockIdx.x & 7). Round-14 counters: VALU 36%, HBM 5.7%,
// MfmaUtil 0.9%, occupancy 41% -> nothing saturated = dependent-load-latency
// bound (csr load -> h1 load chain, only 4 in flight). THIS ROUND: unroll-8
// with grouped issue (8 csr loads, then 8 h1 loads, then adds) to double MLP.
// No min-occupancy bound (round-12: forced VGPR cap -> 287MB spill).
__launch_bounds__(256)
__global__ void k_l2f(const int* __restrict__ offs, const int* __restrict__ deg,
                      const int* __restrict__ csr, const uint4* __restrict__ h1all,
                      const float* __restrict__ dinv, const float* __restrict__ W2,
                      const float* __restrict__ b2, float* __restrict__ ppool) {
  __shared__ __align__(16) unsigned int As2[64 * 36];  // 9.2 KB bf16 pairs
  __shared__ __align__(16) unsigned int WsT[64 * 36];  // 9.2 KB W2^T bf16 pairs
  __shared__ float pool[64];
  int tid = threadIdx.x;
  int t = blockIdx.x & 7;
  int rows0 = (blockIdx.x >> 3) * 64;
  const uint4* h1v = h1all + (size_t)t * NND * 4;
  if (tid < 64) pool[tid] = 0.f;
  // WsT[j][k] = bf16(W2[k][j]); uint j*36+k2 = pair (k=2k2, 2k2+1)
  for (int i = 0; i < 8; ++i) {
    int p2 = i * 256 + tid;           // [0, 2048)
    int j = p2 >> 5, k2 = p2 & 31;
    WsT[j * 36 + k2] = pkbf(W2[(2 * k2) * 64 + j], W2[(2 * k2 + 1) * 64 + j]);
  }

  // ---- phase 1: gather (node row = tid>>2, q = tid&3 -> k = q*16+m) ----
  int row = tid >> 2, q = tid & 3;
  int n = rows0 + row;
  f32x2 acc2[8];
#pragma unroll
  for (int m = 0; m < 8; ++m) acc2[m] = (f32x2)(0.f);
  if (n < NND) {
    int o0 = offs[n], d = deg[n];
    int i = 0;
    for (; i + 8 <= d; i += 8) {
      int s[8];
#pragma unroll
      for (int u = 0; u < 8; ++u) s[u] = csr[o0 + i + u];
      uint4 uu[8];
#pragma unroll
      for (int u = 0; u < 8; ++u) uu[u] = h1v[(size_t)s[u] * 4 + q];
#pragma unroll
      for (int u = 0; u < 8; ++u) { ACCPK(uu[u]); }
    }
    for (; i + 4 <= d; i += 4) {
      int s[4];
#pragma unroll
      for (int u = 0; u < 4; ++u) s[u] = csr[o0 + i + u];
      uint4 uu[4];
#pragma unroll
      for (int u = 0; u < 4; ++u) uu[u] = h1v[(size_t)s[u] * 4 + q];
#pragma unroll
      for (int u = 0; u < 4; ++u) { ACCPK(uu[u]); }
    }
    for (; i < d; ++i) {
      uint4 u = h1v[(size_t)csr[o0 + i] * 4 + q];
      ACCPK(u);
    }
  }
  float dn = (n < NND) ? dinv[n] : 0.f;
  // pack 16 f32 -> 8 uints (bf16 pairs); uint u=q*8+j*2 holds k=2u,2u+1
#pragma unroll
  for (int j = 0; j < 4; ++j) {
    uint2 s;
    s.x = pkbf(acc2[2 * j].x * dn, acc2[2 * j].y * dn);
    s.y = pkbf(acc2[2 * j + 1].x * dn, acc2[2 * j + 1].y * dn);
    *(uint2*)&As2[row * 36 + q * 8 + j * 2] = s;
  }
  __syncthreads();

  // ---- phase 2: MFMA. wave w: rows 16w..16w+15; 4 col-tiles x 2 K-steps ----
  int w = tid >> 6, l = tid & 63;
  int lr = l & 15, lg = l >> 4;
  f32x4 dacc[4];
#pragma unroll
  for (int ct = 0; ct < 4; ++ct) dacc[ct] = (f32x4)(0.f);
#pragma unroll
  for (int kk = 0; kk < 2; ++kk) {
    // A-frag: row 16w+lr, k = kk*32 + lg*8 + j  -> uint off kk*16 + lg*4
    bf16x8 af = *(const bf16x8*)&As2[(16 * w + lr) * 36 + kk * 16 + lg * 4];
#pragma unroll
    for (int ct = 0; ct < 4; ++ct) {
      bf16x8 bf = *(const bf16x8*)&WsT[(ct * 16 + lr) * 36 + kk * 16 + lg * 4];
      dacc[ct] = __builtin_amdgcn_mfma_f32_16x16x32_bf16(af, bf, dacc[ct], 0, 0, 0);
    }
  }
  // epilogue: D row = 16w + lg*4 + r, col = ct*16 + lr. relu+bias, row-sum.
  int growbase = rows0 + 16 * w + lg * 4;
#pragma unroll
  for (int ct = 0; ct < 4; ++ct) {
    float bb = b2[ct * 16 + lr];
    float s = 0.f;
#pragma unroll
    for (int r = 0; r < 4; ++r)
      if (growbase + r < NND) s += fmaxf(dacc[ct][r] + bb, 0.f);
    s += __shfl_xor(s, 16);
    s += __shfl_xor(s, 32);
    if (l < 16) atomicAdd(&pool[ct * 16 + lr], s);
  }
  __syncthreads();
  if (tid < 64) atomicAdd(&ppool[t * 64 + tid], pool[tid]);
}

// ---------------- GRU + fc ----------------

__global__ void k_twih(const float* __restrict__ w, float* __restrict__ wt) {
  int g = blockIdx.x * 256 + threadIdx.x;
  if (g < 384 * 64) { int r = g >> 6, k = g & 63; wt[k * 384 + r] = w[g]; }
}
__global__ void k_twhh(const float* __restrict__ w, float* __restrict__ wt) {
  int g = blockIdx.x * 256 + threadIdx.x;
  if (g < 384 * 128) { int r = g >> 7, k = g & 127; wt[k * 384 + r] = w[g]; }
}

__launch_bounds__(384, 2)
__global__ void k_gru(const float* __restrict__ ppool, const float* __restrict__ wihT,
                      const float* __restrict__ whhT, const float* __restrict__ b_ih,
                      const float* __restrict__ b_hh, const float* __restrict__ fc_w,
                      const float* __restrict__ fc_b, float* __restrict__ out) {
  __shared__ float x[64], h[128], gi_s[384], gh_s[384], red[128];
  int j = threadIdx.x;  // 0..383
  float wih[64];
#pragma unroll
  for (int k = 0; k < 64; ++k) wih[k] = wihT[k * 384 + j];
  float whh[128];
#pragma unroll
  for (int k = 0; k < 128; ++k) whh[k] = whhT[k * 384 + j];
  float bi = b_ih[j], bh2 = b_hh[j];
  if (j < 128) h[j] = 0.f;
  const float invn = 1.0f / (float)NND;
  for (int t = 0; t < TT; ++t) {
    if (j < 64) x[j] = ppool[t * 64 + j] * invn;
    __syncthreads();
    float gi = bi, gh = bh2;
#pragma unroll
    for (int k4 = 0; k4 < 16; ++k4) {
      float4 xv = *(const float4*)&x[k4 * 4];
      gi = fmaf(wih[k4 * 4 + 0], xv.x, gi);
      gi = fmaf(wih[k4 * 4 + 1], xv.y, gi);
      gi = fmaf(wih[k4 * 4 + 2], xv.z, gi);
      gi = fmaf(wih[k4 * 4 + 3], xv.w, gi);
    }
#pragma unroll
    for (int k4 = 0; k4 < 32; ++k4) {
      float4 hv = *(const float4*)&h[k4 * 4];
      gh = fmaf(whh[k4 * 4 + 0], hv.x, gh);
      gh = fmaf(whh[k4 * 4 + 1], hv.y, gh);
      gh = fmaf(whh[k4 * 4 + 2], hv.z, gh);
      gh = fmaf(whh[k4 * 4 + 3], hv.w, gh);
    }
    gi_s[j] = gi;
    gh_s[j] = gh;
    __syncthreads();
    if (j < 128) {
      float r = 1.f / (1.f + expf(-(gi_s[j] + gh_s[j])));
      float z = 1.f / (1.f + expf(-(gi_s[128 + j] + gh_s[128 + j])));
      float nn = tanhf(gi_s[256 + j] + r * gh_s[256 + j]);
      h[j] = (1.f - z) * nn + z * h[j];
    }
    __syncthreads();
  }
  if (j < 128) red[j] = h[j] * fc_w[j];
  __syncthreads();
  for (int o = 64; o > 0; o >>= 1) {
    if (j < o) red[j] += red[j + o];
    __syncthreads();
  }
  if (j == 0) out[0] = red[0] + fc_b[0];
}

// ---------------- launch ----------------

extern "C" void kernel_launch(void* const* d_in, const int* in_sizes, int n_in,
                              void* d_out, int out_size, void* d_ws, size_t ws_size,
                              hipStream_t stream) {
  const float* x_seq = (const float*)d_in[0];
  const int*   ei    = (const int*)d_in[1];
  const float* W1    = (const float*)d_in[2];
  const float* b1    = (const float*)d_in[3];
  const float* W2    = (const float*)d_in[4];
  const float* b2    = (const float*)d_in[5];
  const float* w_ih  = (const float*)d_in[6];
  const float* w_hh  = (const float*)d_in[7];
  const float* b_ih  = (const float*)d_in[8];
  const float* b_hh  = (const float*)d_in[9];
  const float* fc_w  = (const float*)d_in[10];
  const float* fc_b  = (const float*)d_in[11];
  float* out = (float*)d_out;

  char* p = (char*)d_ws;
  size_t off = 0;
  auto carve = [&](size_t bytes) -> char* {
    char* q = p + off;
    off += (bytes + 255) & ~(size_t)255;
    return q;
  };
  int*   deg    = (int*)carve((size_t)NND * 4);
  float* dinv   = (float*)carve((size_t)NND * 4);
  int*   offs   = (int*)carve((size_t)NND * 4);
  int*   bsum   = (int*)carve(256 * 4);
  int*   boff   = (int*)carve(256 * 4);
  int*   csr    = (int*)carve((size_t)(NE + NND) * 4);
  uint2* xs2    = (uint2*)carve((size_t)NND * 8 * 8);        // 3.2 MB
  float* ppool  = (float*)carve((size_t)TT * 64 * 4);
  float* wihT   = (float*)carve((size_t)384 * 64 * 4);
  float* whhT   = (float*)carve((size_t)384 * 128 * 4);
  char*  tail   = carve((size_t)TT * NND * 64);              // 25.6 MB: h1all
  uint4* h1all  = (uint4*)tail;
  int*   rank   = (int*)tail;   // alias: rank dead before h1all's first write

  k_init<<<NBS, 256, 0, stream>>>(deg, ppool);
  k_deg<<<(NE + 255) / 256, 256, 0, stream>>>(ei, deg, rank);
  k_dinv<<<NBS, 256, 0, stream>>>(deg, dinv);
  k_scan1<<<NBS, 256, 0, stream>>>(deg, bsum);
  k_scan2<<<1, 256, 0, stream>>>(bsum, boff);
  k_scan3<<<NBS, 256, 0, stream>>>(deg, boff, offs, csr);
  // 2 atomic-free dst-range passes (csr window ~3.3MB, L2-resident)
  for (int pp = 0; pp < 2; ++pp) {
    int lo = pp * (NND / 2), hi = (pp == 1) ? NND : (NND / 2);
    k_scatter<<<(NE + 255) / 256, 256, 0, stream>>>(ei, offs, rank, csr, lo, hi);
  }
  k_xsb<<<(NND * TT + 255) / 256, 256, 0, stream>>>(x_seq, dinv, xs2);
  k_twih<<<(384 * 64 + 255) / 256, 256, 0, stream>>>(w_ih, wihT);
  k_twhh<<<(384 * 128 + 255) / 256, 256, 0, stream>>>(w_hh, whhT);
  // fused layer-1, all t (rank dead from here; h1all reuses its space)
  k_yh1<<<(NND * 4 + 255) / 256, 256, 0, stream>>>(offs, deg, csr,
                                                   (const uint4*)xs2, dinv,
                                                   W1, b1, h1all);
  // fused layer-2 + pool, ALL t, XCD-pinned t-slices, MFMA phase-2
  k_l2f<<<TT * NBT2, 256, 0, stream>>>(offs, deg, csr, h1all, dinv, W2, b2, ppool);

  k_gru<<<1, 384, 0, stream>>>(ppool, wihT, whhT, b_ih, b_hh, fc_w, fc_b, out);
}